// Round 6
// baseline (296.965 us; speedup 1.0000x reference)
//
#include <hip/hip_runtime.h>
#include <math.h>

#define DIM 256
#define NUM_EMB 1024
#define ROWS 16384
#define NCH 8            // codebook chunks (128 rows / 64KB each)
#define NUMEL 4194304.0f // 8*2048*256

// DIAGNOSTIC ROUND: rep-loops inflate each kernel past the ~44us poison-fill
// threshold so rocprof top-5 shows OUR kernels' counters. Idempotent: every
// rep recomputes and rewrites identical values. Remove loops next round.
#define REP_PREP 16
#define REP_MAIN 8
#define REP_FIN  8

typedef __attribute__((ext_vector_type(8))) short bf16x8;
typedef __attribute__((ext_vector_type(4))) float f32x4;

// f32 -> bf16 round-to-nearest-even (bit pattern)
__device__ __forceinline__ unsigned short f2bf(float f) {
    unsigned int u = __float_as_uint(f);
    u = (u + 0x7FFFu + ((u >> 16) & 1u)) >> 16;
    return (unsigned short)u;
}

// ws layout (bytes):
//   Ebf : [0,        524288)   bf16 codebook, fragment-linear
//   Xbf : [524288,   8912896)  bf16 inputs, fragment-linear
//   esq : [8912896,  8916992)  f32 [1024]
//   xsq : [8916992,  8982528)  f32 [16384]
//   pval: [8982528,  9506816)  f32 [16384][8]
//   pidx: [9506816, 10031104)  int [16384][8]
//   bsum: [10031104,10047488)  f32 [4096]

__global__ __launch_bounds__(256) void kprep(
        const float* __restrict__ src, unsigned short* __restrict__ dst,
        float* __restrict__ sq) {
    #pragma unroll 1
    for (int rep = 0; rep < REP_PREP; ++rep) {
        asm volatile("" ::: "memory");
        int t = blockIdx.x * 4 + (threadIdx.x >> 6);
        int l = threadIdx.x & 63;
        int r = l & 15, g = l >> 4;
        const float* rp = src + (t * 16 + r) * DIM + g * 8;
        float s = 0.f;
        #pragma unroll
        for (int kc = 0; kc < 8; ++kc) {
            float4 v0 = *(const float4*)(rp + kc * 32);
            float4 v1 = *(const float4*)(rp + kc * 32 + 4);
            bf16x8 o;
            o[0] = f2bf(v0.x); o[1] = f2bf(v0.y); o[2] = f2bf(v0.z); o[3] = f2bf(v0.w);
            o[4] = f2bf(v1.x); o[5] = f2bf(v1.y); o[6] = f2bf(v1.z); o[7] = f2bf(v1.w);
            *(bf16x8*)(dst + (t * 8 + kc) * 512 + l * 8) = o;
            s += v0.x*v0.x + v0.y*v0.y + v0.z*v0.z + v0.w*v0.w
               + v1.x*v1.x + v1.y*v1.y + v1.z*v1.z + v1.w*v1.w;
        }
        s += __shfl_xor(s, 16);
        s += __shfl_xor(s, 32);
        if (g == 0) sq[t * 16 + r] = s;
    }
}

__global__ __launch_bounds__(256) void kmain(
        const unsigned short* __restrict__ Xbf,
        const unsigned short* __restrict__ Ebf,
        const float* __restrict__ esq,
        float* __restrict__ pval, int* __restrict__ pidx) {
    __shared__ unsigned short Eb[32768];   // 64 KB

    int tid  = threadIdx.x;
    int wid  = tid >> 6;
    int lane = tid & 63;
    int r15  = lane & 15;
    int g    = lane >> 4;
    int chunk = blockIdx.x & (NCH - 1);
    int mg    = blockIdx.x >> 3;

    #pragma unroll 1
    for (int rep = 0; rep < REP_MAIN; ++rep) {
        asm volatile("" ::: "memory");
        __syncthreads();   // protect LDS across reps
        {
            const char* gs = (const char*)(Ebf + chunk * 32768);
            char* ls = (char*)Eb;
            #pragma unroll
            for (int i = 0; i < 16; ++i) {
                int off = i * 4096 + tid * 16;
                __builtin_amdgcn_global_load_lds(
                    (const __attribute__((address_space(1))) unsigned int*)(gs + off),
                    (__attribute__((address_space(3))) unsigned int*)(ls + off),
                    16, 0, 0);
            }
        }

        int t0 = mg * 8 + wid * 2;
        bf16x8 a0[8], a1[8];
        #pragma unroll
        for (int kc = 0; kc < 8; ++kc) {
            a0[kc] = *(const bf16x8*)(Xbf + ((t0 + 0) * 8 + kc) * 512 + lane * 8);
            a1[kc] = *(const bf16x8*)(Xbf + ((t0 + 1) * 8 + kc) * 512 + lane * 8);
        }
        __syncthreads();   // drains vmcnt (staging + A loads)

        float bv0[4] = {INFINITY,INFINITY,INFINITY,INFINITY};
        float bv1[4] = {INFINITY,INFINITY,INFINITY,INFINITY};
        int   bi0[4] = {0,0,0,0}, bi1[4] = {0,0,0,0};

        #pragma unroll
        for (int s = 0; s < 8; s += 2) {
            bf16x8 b0[8], b1[8];
            #pragma unroll
            for (int kc = 0; kc < 8; ++kc) {
                b0[kc] = *(const bf16x8*)(Eb + (s + 0) * 2048 + kc * 512 + lane * 8);
                b1[kc] = *(const bf16x8*)(Eb + (s + 1) * 2048 + kc * 512 + lane * 8);
            }
            float es0 = esq[chunk * 128 + (s + 0) * 16 + r15];
            float es1 = esq[chunk * 128 + (s + 1) * 16 + r15];
            f32x4 c00 = {0.f,0.f,0.f,0.f}, c01 = {0.f,0.f,0.f,0.f};
            f32x4 c10 = {0.f,0.f,0.f,0.f}, c11 = {0.f,0.f,0.f,0.f};
            #pragma unroll
            for (int kc = 0; kc < 8; ++kc) {
                c00 = __builtin_amdgcn_mfma_f32_16x16x32_bf16(a0[kc], b0[kc], c00, 0, 0, 0);
                c10 = __builtin_amdgcn_mfma_f32_16x16x32_bf16(a1[kc], b0[kc], c10, 0, 0, 0);
                c01 = __builtin_amdgcn_mfma_f32_16x16x32_bf16(a0[kc], b1[kc], c01, 0, 0, 0);
                c11 = __builtin_amdgcn_mfma_f32_16x16x32_bf16(a1[kc], b1[kc], c11, 0, 0, 0);
            }
            int br0 = chunk * 128 + (s + 0) * 16 + r15;
            int br1 = br0 + 16;
            #pragma unroll
            for (int r = 0; r < 4; ++r) {
                float v;
                v = fmaf(-2.f, c00[r], es0); if (v < bv0[r]) { bv0[r] = v; bi0[r] = br0; }
                v = fmaf(-2.f, c01[r], es1); if (v < bv0[r]) { bv0[r] = v; bi0[r] = br1; }
                v = fmaf(-2.f, c10[r], es0); if (v < bv1[r]) { bv1[r] = v; bi1[r] = br0; }
                v = fmaf(-2.f, c11[r], es1); if (v < bv1[r]) { bv1[r] = v; bi1[r] = br1; }
            }
        }

        #pragma unroll
        for (int m = 1; m <= 8; m <<= 1) {
            #pragma unroll
            for (int r = 0; r < 4; ++r) {
                float ov; int oi;
                ov = __shfl_xor(bv0[r], m); oi = __shfl_xor(bi0[r], m);
                if (ov < bv0[r] || (ov == bv0[r] && oi < bi0[r])) { bv0[r] = ov; bi0[r] = oi; }
                ov = __shfl_xor(bv1[r], m); oi = __shfl_xor(bi1[r], m);
                if (ov < bv1[r] || (ov == bv1[r] && oi < bi1[r])) { bv1[r] = ov; bi1[r] = oi; }
            }
        }
        if (r15 == 0) {
            #pragma unroll
            for (int r = 0; r < 4; ++r) {
                int row0 = mg * 128 + wid * 32 + g * 4 + r;
                int row1 = row0 + 16;
                pval[row0 * NCH + chunk] = bv0[r];
                pidx[row0 * NCH + chunk] = bi0[r];
                pval[row1 * NCH + chunk] = bv1[r];
                pidx[row1 * NCH + chunk] = bi1[r];
            }
        }
    }
}

__global__ __launch_bounds__(256) void kfinal(
        const float* __restrict__ pval, const int* __restrict__ pidx,
        const float* __restrict__ xsq, const float* __restrict__ E,
        float* __restrict__ outq, float* __restrict__ bsum) {
    __shared__ float ls[4];
    int tid  = threadIdx.x;
    int wid  = tid >> 6;
    int lane = tid & 63;
    int row  = blockIdx.x * 4 + wid;

    #pragma unroll 1
    for (int rep = 0; rep < REP_FIN; ++rep) {
        asm volatile("" ::: "memory");
        __syncthreads();
        float v = INFINITY; int i = 0;
        if (lane < NCH) { v = pval[row * NCH + lane]; i = pidx[row * NCH + lane]; }
        #pragma unroll
        for (int m = 1; m <= 4; m <<= 1) {
            float ov = __shfl_xor(v, m);
            int   oi = __shfl_xor(i, m);
            if (ov < v || (ov == v && oi < i)) { v = ov; i = oi; }
        }
        int idx = __shfl(i, 0);

        #pragma unroll
        for (int j = 0; j < 4; ++j)
            outq[row * DIM + j * 64 + lane] = E[idx * DIM + j * 64 + lane];

        if (lane == 0) ls[wid] = xsq[row] + v;
        __syncthreads();
        if (tid == 0) bsum[blockIdx.x] = ls[0] + ls[1] + ls[2] + ls[3];
    }
}

__global__ __launch_bounds__(1024) void k3_loss(
        const float* __restrict__ bsum, float* __restrict__ out) {
    __shared__ float ls[16];
    int t = threadIdx.x;
    float s = bsum[t] + bsum[t + 1024] + bsum[t + 2048] + bsum[t + 3072];
    #pragma unroll
    for (int m = 1; m <= 32; m <<= 1) s += __shfl_xor(s, m);
    int wid = t >> 6, lane = t & 63;
    if (lane == 0) ls[wid] = s;
    __syncthreads();
    if (wid == 0) {
        float v = (lane < 16) ? ls[lane] : 0.f;
        #pragma unroll
        for (int m = 1; m <= 8; m <<= 1) v += __shfl_xor(v, m);
        if (lane == 0) out[0] = 1.25f * v * (1.0f / NUMEL);
    }
}

extern "C" void kernel_launch(void* const* d_in, const int* in_sizes, int n_in,
                              void* d_out, int out_size, void* d_ws, size_t ws_size,
                              hipStream_t stream) {
    const float* X = (const float*)d_in[0];   // [8,2048,256] f32
    const float* E = (const float*)d_in[1];   // [1024,256]   f32
    float* out = (float*)d_out;               // [1 + 4194304] f32
    char* ws = (char*)d_ws;

    unsigned short* Ebf = (unsigned short*)ws;
    unsigned short* Xbf = (unsigned short*)(ws + 524288);
    float* esq  = (float*)(ws + 8912896);
    float* xsq  = (float*)(ws + 8916992);
    float* pval = (float*)(ws + 8982528);
    int*   pidx = (int*)(ws + 9506816);
    float* bsum = (float*)(ws + 10031104);

    kprep<<<NUM_EMB / 64, 256, 0, stream>>>(E, Ebf, esq);
    kprep<<<ROWS / 64, 256, 0, stream>>>(X, Xbf, xsq);
    kmain<<<(ROWS / 128) * NCH, 256, 0, stream>>>(Xbf, Ebf, esq, pval, pidx);
    kfinal<<<ROWS / 4, 256, 0, stream>>>(pval, pidx, xsq, E, out + 1, bsum);
    k3_loss<<<1, 1024, 0, stream>>>(bsum, out);
}

// Round 7
// 96.817 us; speedup vs baseline: 3.0673x; 3.0673x over previous
//
#include <hip/hip_runtime.h>
#include <math.h>

#define DIM 256
#define NUM_EMB 1024
#define ROWS 16384
#define NCH 16           // codebook chunks (64 rows / 32KB each)
#define NUMEL 4194304.0f // 8*2048*256

typedef __attribute__((ext_vector_type(8))) short bf16x8;
typedef __attribute__((ext_vector_type(4))) float f32x4;

// f32 -> bf16 round-to-nearest-even (bit pattern)
__device__ __forceinline__ unsigned short f2bf(float f) {
    unsigned int u = __float_as_uint(f);
    u = (u + 0x7FFFu + ((u >> 16) & 1u)) >> 16;
    return (unsigned short)u;
}

// ws layout (bytes):
//   Ebf : [0,       524288)   bf16 codebook, fragment-linear:
//         subtile t=row/16, kc=dim/32 -> 1024B block; lane l=16g+r holds
//         row t*16+r, dims [kc*32+8g,+8) at ushort off (t*8+kc)*512 + l*8
//   Xbf : [524288,  8912896)  bf16 inputs, same layout (1024 subtiles)
//   pval: [8912896, 9961472)  f32 [16384][16] packed (dot | idx) per chunk
//   bsum: [9961472, 9977856)  f32 [4096] per-block loss partials

// ---- kprep: f32 rows -> fragment-linear bf16 --------------------------
__global__ __launch_bounds__(256) void kprep(
        const float* __restrict__ src, unsigned short* __restrict__ dst) {
    int t = blockIdx.x * 4 + (threadIdx.x >> 6);
    int l = threadIdx.x & 63;
    int r = l & 15, g = l >> 4;
    const float* rp = src + (t * 16 + r) * DIM + g * 8;
    #pragma unroll
    for (int kc = 0; kc < 8; ++kc) {
        float4 v0 = *(const float4*)(rp + kc * 32);
        float4 v1 = *(const float4*)(rp + kc * 32 + 4);
        bf16x8 o;
        o[0] = f2bf(v0.x); o[1] = f2bf(v0.y); o[2] = f2bf(v0.z); o[3] = f2bf(v0.w);
        o[4] = f2bf(v1.x); o[5] = f2bf(v1.y); o[6] = f2bf(v1.z); o[7] = f2bf(v1.w);
        *(bf16x8*)(dst + (t * 8 + kc) * 512 + l * 8) = o;
    }
}

// ---- kmain: packed-argmax of dot over one 64-row codebook chunk -------
// grid 2048 = 128 mgroups (fast) x 16 chunks. 4 waves; wave owns 2
// M-subtiles (32 rows); chunk (4 subtiles, 32KB) staged in LDS.
// Score = dot(x,e); index packed into low 10 mantissa bits -> v_max only.
__global__ __launch_bounds__(256) void kmain(
        const unsigned short* __restrict__ Xbf,
        const unsigned short* __restrict__ Ebf,
        float* __restrict__ pval) {
    __shared__ unsigned short Eb[16384];   // 32 KB

    int tid  = threadIdx.x;
    int wid  = tid >> 6;
    int lane = tid & 63;
    int r15  = lane & 15;
    int g    = lane >> 4;
    int mg    = blockIdx.x & 127;          // same-mg blocks -> same XCD
    int chunk = blockIdx.x >> 7;

    // async stage: 32KB codebook chunk -> LDS (linear)
    {
        const char* gs = (const char*)(Ebf + chunk * 16384);
        char* ls = (char*)Eb;
        #pragma unroll
        for (int i = 0; i < 8; ++i) {
            int off = i * 4096 + tid * 16;
            __builtin_amdgcn_global_load_lds(
                (const __attribute__((address_space(1))) unsigned int*)(gs + off),
                (__attribute__((address_space(3))) unsigned int*)(ls + off),
                16, 0, 0);
        }
    }

    // A fragments (overlaps staging): 2 subtiles = 32 rows
    int t0 = mg * 8 + wid * 2;
    bf16x8 a0[8], a1[8];
    #pragma unroll
    for (int kc = 0; kc < 8; ++kc) {
        a0[kc] = *(const bf16x8*)(Xbf + ((t0 + 0) * 8 + kc) * 512 + lane * 8);
        a1[kc] = *(const bf16x8*)(Xbf + ((t0 + 1) * 8 + kc) * 512 + lane * 8);
    }
    __syncthreads();   // drains vmcnt (staging + A loads)

    float bv0[4] = {-INFINITY,-INFINITY,-INFINITY,-INFINITY};
    float bv1[4] = {-INFINITY,-INFINITY,-INFINITY,-INFINITY};

    #pragma unroll
    for (int s = 0; s < 4; ++s) {
        bf16x8 b[8];
        #pragma unroll
        for (int kc = 0; kc < 8; ++kc)
            b[kc] = *(const bf16x8*)(Eb + s * 2048 + kc * 512 + lane * 8);
        f32x4 c0 = {0.f,0.f,0.f,0.f}, c1 = {0.f,0.f,0.f,0.f};
        #pragma unroll
        for (int kc = 0; kc < 8; ++kc) {
            c0 = __builtin_amdgcn_mfma_f32_16x16x32_bf16(a0[kc], b[kc], c0, 0, 0, 0);
            c1 = __builtin_amdgcn_mfma_f32_16x16x32_bf16(a1[kc], b[kc], c1, 0, 0, 0);
        }
        int bidx = chunk * 64 + s * 16 + r15;   // codebook row, 10 bits
        #pragma unroll
        for (int r = 0; r < 4; ++r) {
            float f0 = __uint_as_float((__float_as_uint(c0[r]) & 0xFFFFFC00u) | bidx);
            bv0[r] = fmaxf(bv0[r], f0);
            float f1 = __uint_as_float((__float_as_uint(c1[r]) & 0xFFFFFC00u) | bidx);
            bv1[r] = fmaxf(bv1[r], f1);
        }
    }

    // max across the 16 lanes of each row-group (index rides along)
    #pragma unroll
    for (int m = 1; m <= 8; m <<= 1) {
        #pragma unroll
        for (int r = 0; r < 4; ++r) {
            bv0[r] = fmaxf(bv0[r], __shfl_xor(bv0[r], m));
            bv1[r] = fmaxf(bv1[r], __shfl_xor(bv1[r], m));
        }
    }
    if (r15 == 0) {
        #pragma unroll
        for (int r = 0; r < 4; ++r) {
            int row0 = mg * 128 + wid * 32 + g * 4 + r;  // C/D: row=(l>>4)*4+reg
            int row1 = row0 + 16;
            pval[row0 * NCH + chunk] = bv0[r];
            pval[row1 * NCH + chunk] = bv1[r];
        }
    }
}

// ---- kfinal: merge chunks, gather E[idx], exact f32 loss, write Q -----
__global__ __launch_bounds__(256) void kfinal(
        const float* __restrict__ pval, const float* __restrict__ X,
        const float* __restrict__ E,
        float* __restrict__ outq, float* __restrict__ bsum) {
    __shared__ float ls[4];
    int tid  = threadIdx.x;
    int wid  = tid >> 6;
    int lane = tid & 63;
    int row  = blockIdx.x * 4 + wid;

    float v = pval[row * NCH + (lane & 15)];   // replicated across 4 groups
    #pragma unroll
    for (int m = 1; m <= 8; m <<= 1) v = fmaxf(v, __shfl_xor(v, m));
    int idx = (int)(__float_as_uint(v) & 1023u);

    float s = 0.f;
    #pragma unroll
    for (int j = 0; j < 4; ++j) {
        float x = X[row * DIM + j * 64 + lane];
        float e = E[idx * DIM + j * 64 + lane];
        outq[row * DIM + j * 64 + lane] = e;   // exact f32 gather
        float d = x - e;
        s = fmaf(d, d, s);
    }
    #pragma unroll
    for (int m = 1; m <= 32; m <<= 1) s += __shfl_xor(s, m);
    if (lane == 0) ls[wid] = s;
    __syncthreads();
    if (tid == 0) bsum[blockIdx.x] = ls[0] + ls[1] + ls[2] + ls[3];
}

// ---- k3: reduce 4096 partials -> loss ---------------------------------
__global__ __launch_bounds__(1024) void k3_loss(
        const float* __restrict__ bsum, float* __restrict__ out) {
    __shared__ float ls[16];
    int t = threadIdx.x;
    float s = bsum[t] + bsum[t + 1024] + bsum[t + 2048] + bsum[t + 3072];
    #pragma unroll
    for (int m = 1; m <= 32; m <<= 1) s += __shfl_xor(s, m);
    int wid = t >> 6, lane = t & 63;
    if (lane == 0) ls[wid] = s;
    __syncthreads();
    if (wid == 0) {
        float v = (lane < 16) ? ls[lane] : 0.f;
        #pragma unroll
        for (int m = 1; m <= 8; m <<= 1) v += __shfl_xor(v, m);
        if (lane == 0) out[0] = 1.25f * v * (1.0f / NUMEL);
    }
}

extern "C" void kernel_launch(void* const* d_in, const int* in_sizes, int n_in,
                              void* d_out, int out_size, void* d_ws, size_t ws_size,
                              hipStream_t stream) {
    const float* X = (const float*)d_in[0];   // [8,2048,256] f32
    const float* E = (const float*)d_in[1];   // [1024,256]   f32
    float* out = (float*)d_out;               // [1 + 4194304] f32
    char* ws = (char*)d_ws;

    unsigned short* Ebf = (unsigned short*)ws;
    unsigned short* Xbf = (unsigned short*)(ws + 524288);
    float* pval = (float*)(ws + 8912896);
    float* bsum = (float*)(ws + 9961472);

    kprep<<<NUM_EMB / 64, 256, 0, stream>>>(E, Ebf);
    kprep<<<ROWS / 64, 256, 0, stream>>>(X, Xbf);
    kmain<<<128 * NCH, 256, 0, stream>>>(Xbf, Ebf, pval);
    kfinal<<<ROWS / 4, 256, 0, stream>>>(pval, X, E, out + 1, bsum);
    k3_loss<<<1, 1024, 0, stream>>>(bsum, out);
}

// Round 9
// 92.510 us; speedup vs baseline: 3.2101x; 1.0466x over previous
//
#include <hip/hip_runtime.h>
#include <math.h>

#define DIM 256
#define NUM_EMB 1024
#define ROWS 16384
#define NCH 16           // codebook chunks (64 rows / 32KB each)
#define NUMEL 4194304.0f // 8*2048*256

typedef __attribute__((ext_vector_type(8))) short bf16x8;
typedef __attribute__((ext_vector_type(4))) float f32x4;

// f32 -> bf16 round-to-nearest-even (bit pattern)
__device__ __forceinline__ unsigned short f2bf(float f) {
    unsigned int u = __float_as_uint(f);
    u = (u + 0x7FFFu + ((u >> 16) & 1u)) >> 16;
    return (unsigned short)u;
}

// ws layout (bytes):
//   Ebf : [0,       524288)   bf16 codebook, fragment-linear:
//         subtile t=row/16, kc=dim/32 -> 1024B block; lane l=16g+r holds
//         row t*16+r, dims [kc*32+8g,+8) at ushort off (t*8+kc)*512 + l*8
//   Xbf : [524288,  8912896)  bf16 inputs, same layout (1024 subtiles)
//   esq : [8912896, 8916992)  f32 [1024]  exact codebook row norms
//   xsq : [8916992, 8982528)  f32 [16384] exact input row norms
//   pval: [8982528,10031104)  f32 [16384][16] packed (dot | idx) per chunk
//   bsum: [10031104,10047488) f32 [4096] per-block loss partials

// ---- kprep: f32 rows -> fragment-linear bf16 + exact row sq-norms -----
// blocks 0..15 -> codebook, blocks 16..271 -> inputs (one launch).
__global__ __launch_bounds__(256) void kprep(
        const float* __restrict__ E, const float* __restrict__ X,
        unsigned short* __restrict__ Ebf, unsigned short* __restrict__ Xbf,
        float* __restrict__ esq, float* __restrict__ xsq) {
    bool isE = blockIdx.x < 16;
    const float* src        = isE ? E   : X;
    unsigned short* dst     = isE ? Ebf : Xbf;
    float* sq               = isE ? esq : xsq;
    int bb                  = isE ? blockIdx.x : blockIdx.x - 16;

    int t = bb * 4 + (threadIdx.x >> 6);
    int l = threadIdx.x & 63;
    int r = l & 15, g = l >> 4;
    const float* rp = src + (t * 16 + r) * DIM + g * 8;
    float s = 0.f;
    #pragma unroll
    for (int kc = 0; kc < 8; ++kc) {
        float4 v0 = *(const float4*)(rp + kc * 32);
        float4 v1 = *(const float4*)(rp + kc * 32 + 4);
        bf16x8 o;
        o[0] = f2bf(v0.x); o[1] = f2bf(v0.y); o[2] = f2bf(v0.z); o[3] = f2bf(v0.w);
        o[4] = f2bf(v1.x); o[5] = f2bf(v1.y); o[6] = f2bf(v1.z); o[7] = f2bf(v1.w);
        *(bf16x8*)(dst + (t * 8 + kc) * 512 + l * 8) = o;
        s += v0.x*v0.x + v0.y*v0.y + v0.z*v0.z + v0.w*v0.w
           + v1.x*v1.x + v1.y*v1.y + v1.z*v1.z + v1.w*v1.w;
    }
    s += __shfl_xor(s, 16);
    s += __shfl_xor(s, 32);
    if (g == 0) sq[t * 16 + r] = s;
}

// ---- kmain: packed-argmax of dot over one 64-row codebook chunk -------
// grid 2048 = 128 mgroups (fast) x 16 chunks. 4 waves; wave owns 2
// M-subtiles (32 rows); chunk (4 subtiles, 32KB) staged in LDS.
// Score = dot(x,e); index packed into low 10 mantissa bits -> v_max only.
__global__ __launch_bounds__(256) void kmain(
        const unsigned short* __restrict__ Xbf,
        const unsigned short* __restrict__ Ebf,
        float* __restrict__ pval) {
    __shared__ unsigned short Eb[16384];   // 32 KB

    int tid  = threadIdx.x;
    int wid  = tid >> 6;
    int lane = tid & 63;
    int r15  = lane & 15;
    int g    = lane >> 4;
    int mg    = blockIdx.x & 127;          // same-mg blocks -> same XCD
    int chunk = blockIdx.x >> 7;

    // async stage: 32KB codebook chunk -> LDS (linear)
    {
        const char* gs = (const char*)(Ebf + chunk * 16384);
        char* ls = (char*)Eb;
        #pragma unroll
        for (int i = 0; i < 8; ++i) {
            int off = i * 4096 + tid * 16;
            __builtin_amdgcn_global_load_lds(
                (const __attribute__((address_space(1))) unsigned int*)(gs + off),
                (__attribute__((address_space(3))) unsigned int*)(ls + off),
                16, 0, 0);
        }
    }

    // A fragments (overlaps staging): 2 subtiles = 32 rows
    int t0 = mg * 8 + wid * 2;
    bf16x8 a0[8], a1[8];
    #pragma unroll
    for (int kc = 0; kc < 8; ++kc) {
        a0[kc] = *(const bf16x8*)(Xbf + ((t0 + 0) * 8 + kc) * 512 + lane * 8);
        a1[kc] = *(const bf16x8*)(Xbf + ((t0 + 1) * 8 + kc) * 512 + lane * 8);
    }
    __syncthreads();   // drains vmcnt (staging + A loads)

    float bv0[4] = {-INFINITY,-INFINITY,-INFINITY,-INFINITY};
    float bv1[4] = {-INFINITY,-INFINITY,-INFINITY,-INFINITY};

    #pragma unroll
    for (int s = 0; s < 4; ++s) {
        bf16x8 b[8];
        #pragma unroll
        for (int kc = 0; kc < 8; ++kc)
            b[kc] = *(const bf16x8*)(Eb + s * 4096 + kc * 512 + lane * 8);
        f32x4 c0 = {0.f,0.f,0.f,0.f}, c1 = {0.f,0.f,0.f,0.f};
        #pragma unroll
        for (int kc = 0; kc < 8; ++kc) {
            c0 = __builtin_amdgcn_mfma_f32_16x16x32_bf16(a0[kc], b[kc], c0, 0, 0, 0);
            c1 = __builtin_amdgcn_mfma_f32_16x16x32_bf16(a1[kc], b[kc], c1, 0, 0, 0);
        }
        int bidx = chunk * 64 + s * 16 + r15;   // codebook row, 10 bits
        #pragma unroll
        for (int r = 0; r < 4; ++r) {
            float f0 = __uint_as_float((__float_as_uint(c0[r]) & 0xFFFFFC00u) | bidx);
            bv0[r] = fmaxf(bv0[r], f0);
            float f1 = __uint_as_float((__float_as_uint(c1[r]) & 0xFFFFFC00u) | bidx);
            bv1[r] = fmaxf(bv1[r], f1);
        }
    }

    // max across the 16 lanes of each row-group (index rides along)
    #pragma unroll
    for (int m = 1; m <= 8; m <<= 1) {
        #pragma unroll
        for (int r = 0; r < 4; ++r) {
            bv0[r] = fmaxf(bv0[r], __shfl_xor(bv0[r], m));
            bv1[r] = fmaxf(bv1[r], __shfl_xor(bv1[r], m));
        }
    }
    if (r15 == 0) {
        #pragma unroll
        for (int r = 0; r < 4; ++r) {
            int row0 = mg * 128 + wid * 32 + g * 4 + r;  // C/D: row=(l>>4)*4+reg
            int row1 = row0 + 16;
            pval[row0 * NCH + chunk] = bv0[r];
            pval[row1 * NCH + chunk] = bv1[r];
        }
    }
}

// ---- kfinal: merge chunks, gather E[idx], loss from norms+dot ---------
__global__ __launch_bounds__(256) void kfinal(
        const float* __restrict__ pval, const float* __restrict__ xsq,
        const float* __restrict__ esq, const float* __restrict__ E,
        float* __restrict__ outq, float* __restrict__ bsum) {
    __shared__ float ls[4];
    int tid  = threadIdx.x;
    int wid  = tid >> 6;
    int lane = tid & 63;
    int row  = blockIdx.x * 4 + wid;

    float v = pval[row * NCH + (lane & 15)];   // replicated across 4 groups
    #pragma unroll
    for (int m = 1; m <= 8; m <<= 1) v = fmaxf(v, __shfl_xor(v, m));
    unsigned vb = __float_as_uint(v);
    int idx    = (int)(vb & 1023u);
    float dotc = __uint_as_float(vb & 0xFFFFFC00u);  // clipped bf16-dot

    #pragma unroll
    for (int j = 0; j < 4; ++j)
        outq[row * DIM + j * 64 + lane] = E[idx * DIM + j * 64 + lane];

    if (lane == 0) ls[wid] = xsq[row] + esq[idx] - 2.f * dotc;  // ||x-e||^2
    __syncthreads();
    if (tid == 0) bsum[blockIdx.x] = ls[0] + ls[1] + ls[2] + ls[3];
}

// ---- k3: reduce 4096 partials -> loss ---------------------------------
__global__ __launch_bounds__(1024) void k3_loss(
        const float* __restrict__ bsum, float* __restrict__ out) {
    __shared__ float ls[16];
    int t = threadIdx.x;
    float s = bsum[t] + bsum[t + 1024] + bsum[t + 2048] + bsum[t + 3072];
    #pragma unroll
    for (int m = 1; m <= 32; m <<= 1) s += __shfl_xor(s, m);
    int wid = t >> 6, lane = t & 63;
    if (lane == 0) ls[wid] = s;
    __syncthreads();
    if (wid == 0) {
        float v = (lane < 16) ? ls[lane] : 0.f;
        #pragma unroll
        for (int m = 1; m <= 8; m <<= 1) v += __shfl_xor(v, m);
        if (lane == 0) out[0] = 1.25f * v * (1.0f / NUMEL);
    }
}

extern "C" void kernel_launch(void* const* d_in, const int* in_sizes, int n_in,
                              void* d_out, int out_size, void* d_ws, size_t ws_size,
                              hipStream_t stream) {
    const float* X = (const float*)d_in[0];   // [8,2048,256] f32
    const float* E = (const float*)d_in[1];   // [1024,256]   f32
    float* out = (float*)d_out;               // [1 + 4194304] f32
    char* ws = (char*)d_ws;

    unsigned short* Ebf = (unsigned short*)ws;
    unsigned short* Xbf = (unsigned short*)(ws + 524288);
    float* esq  = (float*)(ws + 8912896);
    float* xsq  = (float*)(ws + 8916992);
    float* pval = (float*)(ws + 8982528);
    float* bsum = (float*)(ws + 10031104);

    kprep<<<16 + ROWS / 64, 256, 0, stream>>>(E, X, Ebf, Xbf, esq, xsq);
    kmain<<<128 * NCH, 256, 0, stream>>>(Xbf, Ebf, pval);
    kfinal<<<ROWS / 4, 256, 0, stream>>>(pval, xsq, esq, E, out + 1, bsum);
    k3_loss<<<1, 1024, 0, stream>>>(bsum, out);
}